// Round 8
// baseline (423.395 us; speedup 1.0000x reference)
//
#include <hip/hip_runtime.h>
#include <cstdint>

#define Ssz 4096
#define Dsz 2048
#define Hn  16
#define Gn  4
#define HDn 128

typedef __attribute__((ext_vector_type(8))) short short8;
typedef __attribute__((ext_vector_type(8))) unsigned short u16x8;
typedef __attribute__((ext_vector_type(4))) float f32x4;

typedef __attribute__((address_space(1))) void gbl_void;
typedef __attribute__((address_space(3))) void lds_void;

static __device__ __forceinline__ unsigned short f2bf(float f) {
  uint32_t u = __builtin_bit_cast(uint32_t, f);
  u += 0x7FFFu + ((u >> 16) & 1u);   // RNE (no NaNs in this workload)
  return (unsigned short)(u >> 16);
}

// global -> LDS direct copy, 16B per lane. LDS dest is wave-uniform base
// (HW adds lane*16); global source address is per-lane.
static __device__ __forceinline__ void gload_lds16(const void* g, void* l) {
  __builtin_amdgcn_global_load_lds((gbl_void*)(uintptr_t)g,
                                   (lds_void*)(uintptr_t)l, 16, 0, 0);
}

// ---------------- cast f32 -> bf16, 8 elems/thread ----------------
__global__ void k_cast_bf16(const float* __restrict__ src,
                            unsigned short* __restrict__ dst, int n) {
  int base = (blockIdx.x * blockDim.x + threadIdx.x) * 8;
  if (base >= n) return;
  float4 a = *reinterpret_cast<const float4*>(src + base);
  float4 b = *reinterpret_cast<const float4*>(src + base + 4);
  u16x8 o;
  o[0] = f2bf(a.x); o[1] = f2bf(a.y); o[2] = f2bf(a.z); o[3] = f2bf(a.w);
  o[4] = f2bf(b.x); o[5] = f2bf(b.y); o[6] = f2bf(b.z); o[7] = f2bf(b.w);
  *reinterpret_cast<u16x8*>(dst + base) = o;
}

// ---------------- transpose f32 (R x C) -> bf16 (C x R), 64x64 tiles ----------------
__global__ void k_transpose(const float* __restrict__ src, int srcStride,
                            unsigned short* __restrict__ dst, int dstStride,
                            int R, int C) {
  __shared__ unsigned short tile[64][65];
  const int r0 = blockIdx.y * 64, c0 = blockIdx.x * 64;
  const int t  = threadIdx.x;
  const int rr = t >> 2;           // 0..63
  const int cc = (t & 3) * 16;     // 0,16,32,48
  const float* sp = src + (size_t)(r0 + rr) * srcStride + c0 + cc;
#pragma unroll
  for (int j = 0; j < 16; j += 4) {
    float4 v = *reinterpret_cast<const float4*>(sp + j);
    tile[rr][cc + j + 0] = f2bf(v.x);
    tile[rr][cc + j + 1] = f2bf(v.y);
    tile[rr][cc + j + 2] = f2bf(v.z);
    tile[rr][cc + j + 3] = f2bf(v.w);
  }
  __syncthreads();
  unsigned short* dp = dst + (size_t)(c0 + rr) * dstStride + r0 + cc;
  u16x8 o0, o1;
#pragma unroll
  for (int j = 0; j < 8; j++) o0[j] = tile[cc + j][rr];
#pragma unroll
  for (int j = 0; j < 8; j++) o1[j] = tile[cc + 8 + j][rr];
  *reinterpret_cast<u16x8*>(dp)     = o0;
  *reinterpret_cast<u16x8*>(dp + 8) = o1;
}

// ---------------- RoPE on Q (cols 0..2047) and K (cols 2048..2559) of Cqkv ----------------
__global__ void k_rope(const float* __restrict__ Cqkv,
                       const float* __restrict__ cosp, const float* __restrict__ sinp,
                       unsigned short* __restrict__ Qb, unsigned short* __restrict__ Kb) {
  const int s = blockIdx.x;
  const float* row = Cqkv + (size_t)s * 3072;
  const float qscale = 0.08838834764831845f;  // 1/sqrt(128)
  for (int c = threadIdx.x; c < 2560; c += 256) {
    int d = c & 127;
    float v = row[c];
    int pc = (d < 64) ? c + 64 : c - 64;
    float pv = row[pc];
    float rot = (d < 64) ? -pv : pv;
    float o = v * cosp[s * 128 + d] + rot * sinp[s * 128 + d];
    if (c < 2048)
      Qb[(size_t)s * 2048 + c] = f2bf(o * qscale);
    else
      Kb[(size_t)s * 512 + (c - 2048)] = f2bf(o);
  }
}

// ---------------- bf16 GEMM v2: 256x256 tile, BK=32, pipelined ----------------
// C(f32, M x N, ldc) = A(M x K) * BT(N x K)^T.
// 8 waves (2M x 4N), wave tile 128x64, acc 8x4 16x16 frags.
// 3-buffer LDS ring (96 KB), staged 2 K-tiles ahead via global_load_lds;
// 2 phases per K-tile (16 MFMA each) with raw barriers; per-wave counted
// vmcnt(4) at K-tile boundary (never 0 mid-loop); setprio around MFMA.
// XCD-aware block swizzle (grid must be a multiple of 8).
__global__ __launch_bounds__(512, 2) void k_gemm256(
    const unsigned short* __restrict__ A, const unsigned short* __restrict__ BT,
    float* __restrict__ C, int M, int N, int K, int ldc) {
  __shared__ __align__(16) unsigned short sA[3][256 * 32];
  __shared__ __align__(16) unsigned short sB[3][256 * 32];
  const int tid = threadIdx.x;                 // 0..511
  const int lane = tid & 63, wid = tid >> 6;   // 8 waves
  const int wr = wid >> 2, wc = wid & 3;       // 2 x 4 wave grid
  const int l15 = lane & 15, lg = lane >> 4;
  const int nbx = N >> 8;
  const int nwg = (M >> 8) * nbx;
  const int bid = blockIdx.x;
  const int swz = (bid & 7) * (nwg >> 3) + (bid >> 3);
  const int m0 = (swz / nbx) << 8, n0 = (swz % nbx) << 8;
  const int nt = K >> 5;

  const int srow = tid >> 2;            // staging row 0..127
  const int scol = (tid & 3) * 8;       // staging col elem

  auto stageA = [&](int t) {
    const int b = t % 3;
    const unsigned short* s0 = A + (size_t)(m0 + srow) * K + t * 32 + scol;
    gload_lds16(s0,                     &sA[b][wid * 512]);
    gload_lds16(s0 + (size_t)128 * K,   &sA[b][4096 + wid * 512]);
  };
  auto stageB = [&](int t) {
    const int b = t % 3;
    const unsigned short* s0 = BT + (size_t)(n0 + srow) * K + t * 32 + scol;
    gload_lds16(s0,                     &sB[b][wid * 512]);
    gload_lds16(s0 + (size_t)128 * K,   &sB[b][4096 + wid * 512]);
  };

  f32x4 acc[8][4] = {};

  // prologue: tiles 0 and 1 in flight; tile 0 guaranteed complete
  stageA(0); stageB(0);
  stageA(1); stageB(1);
  asm volatile("s_waitcnt vmcnt(4)" ::: "memory");
  __builtin_amdgcn_s_barrier();

  for (int t = 0; t < nt; t++) {
    const int bt = t % 3;
    const unsigned short* a_base = &sA[bt][0];
    const unsigned short* b_base = &sB[bt][0];
    short8 af[4], bf[4];
    // ---- phase 0: B frags + A frags (mf 0-3), stage A of t+2 ----
#pragma unroll
    for (int nf = 0; nf < 4; nf++)
      bf[nf] = *reinterpret_cast<const short8*>(
          b_base + (wc * 64 + nf * 16 + l15) * 32 + lg * 8);
#pragma unroll
    for (int mf = 0; mf < 4; mf++)
      af[mf] = *reinterpret_cast<const short8*>(
          a_base + (wr * 128 + mf * 16 + l15) * 32 + lg * 8);
    if (t + 2 < nt) stageA(t + 2);
    __builtin_amdgcn_s_barrier();
    __builtin_amdgcn_s_setprio(1);
#pragma unroll
    for (int mf = 0; mf < 4; mf++)
#pragma unroll
      for (int nf = 0; nf < 4; nf++)
        acc[mf][nf] = __builtin_amdgcn_mfma_f32_16x16x32_bf16(
            af[mf], bf[nf], acc[mf][nf], 0, 0, 0);
    __builtin_amdgcn_s_setprio(0);
    __builtin_amdgcn_s_barrier();
    // ---- phase 1: A frags (mf 4-7), stage B of t+2 ----
#pragma unroll
    for (int mf = 0; mf < 4; mf++)
      af[mf] = *reinterpret_cast<const short8*>(
          a_base + (wr * 128 + 64 + mf * 16 + l15) * 32 + lg * 8);
    if (t + 2 < nt) stageB(t + 2);
    __builtin_amdgcn_s_barrier();
    __builtin_amdgcn_s_setprio(1);
#pragma unroll
    for (int mf = 0; mf < 4; mf++)
#pragma unroll
      for (int nf = 0; nf < 4; nf++)
        acc[4 + mf][nf] = __builtin_amdgcn_mfma_f32_16x16x32_bf16(
            af[mf], bf[nf], acc[4 + mf][nf], 0, 0, 0);
    __builtin_amdgcn_s_setprio(0);
    // ---- K-tile boundary: ensure tile t+1 resident; keep t+2 in flight ----
    if (t + 2 < nt) {
      asm volatile("s_waitcnt vmcnt(4)" ::: "memory");
    } else {
      asm volatile("s_waitcnt vmcnt(0)" ::: "memory");
    }
    __builtin_amdgcn_s_barrier();
  }

  const int rbase = m0 + wr * 128 + lg * 4;
  const int cbase = n0 + wc * 64 + l15;
#pragma unroll
  for (int mf = 0; mf < 8; mf++)
#pragma unroll
    for (int nf = 0; nf < 4; nf++)
#pragma unroll
      for (int r = 0; r < 4; r++)
        C[(size_t)(rbase + mf * 16 + r) * ldc + cbase + nf * 16] = acc[mf][nf][r];
}

// ---------------- causal GQA flash attention, v4 ----------------
// Swapped QK^T: sc = mfma(K, Q) -> lane holds S[kv=f*16+lg*4+r][q=l15].
// Row softmax is in-lane (15 ops) + 2 shfl_xor; stats are per-lane scalars.
// P packed to bf16 pairs in-register, 4x ds_write_b64 (kv-contiguous rows),
// same XOR swizzle both sides, 2x ds_read_b128 back as PV A-frags.
__global__ __launch_bounds__(512, 4) void k_attn(
    const unsigned short* __restrict__ Qb, const unsigned short* __restrict__ Kb,
    const unsigned short* __restrict__ Vt, unsigned short* __restrict__ ctx) {
  __shared__ __align__(16) char sK[2][16384];   // [buf][64 kv][256B], swizzled
  __shared__ __align__(16) char sV[2][16384];   // [buf][128 d][128B], swizzled
  __shared__ __align__(16) char sP[8][2048];    // [wave][16 q][128B], swizzled
  const int id = blockIdx.x;                    // 0..511
  const int kid = id & 255;
  const int h = kid & 15, g = h >> 2;
  const int j = kid >> 4;                       // 0..15
  const int qt = (id < 256) ? (31 - j) : j;     // long blocks first
  const int qb = qt * 128;
  const int lane = threadIdx.x & 63, wid = threadIdx.x >> 6;
  const int l15 = lane & 15, lg = lane >> 4;
  const int sw = (l15 & 7) << 4;
  const int wmin = qb + wid * 16;
  const int nt = qt * 2 + 2;

  // per-lane pre-swizzled staging source offsets (bytes)
  const char* kbyte = (const char*)Kb;
  const char* vbyte = (const char*)Vt;
  int kOff[2], vOff[2];
#pragma unroll
  for (int q = 0; q < 2; q++) {
    int rk = wid * 8 + q * 4 + (lane >> 4);             // K tile row 0..63
    kOff[q] = rk * 1024 + g * 256 + (((lane & 15) * 16) ^ ((rk & 7) << 4));
    int rv = wid * 16 + q * 8 + (lane >> 3);            // V tile row (d) 0..127
    vOff[q] = (g * 128 + rv) * 8192 + (((lane & 7) * 16) ^ ((rv & 7) << 4));
  }

  auto stage = [&](int t, int b) {
    const char* ks = kbyte + (size_t)t * 65536;   // kv0*1024
    const char* vs = vbyte + (size_t)t * 128;     // kv0*2
#pragma unroll
    for (int q = 0; q < 2; q++)
      gload_lds16(ks + kOff[q], &sK[b][(wid * 2 + q) * 1024]);
#pragma unroll
    for (int q = 0; q < 2; q++)
      gload_lds16(vs + vOff[q], &sV[b][(wid * 2 + q) * 1024]);
  };

  // hoist Q fragments (L2-resident); B-operand layout: col=q=l15, k=lg*8+i
  short8 qf[4];
  {
    const unsigned short* qp = Qb + (size_t)(wmin + l15) * Dsz + h * HDn + lg * 8;
#pragma unroll
    for (int kk = 0; kk < 4; kk++)
      qf[kk] = *reinterpret_cast<const short8*>(qp + kk * 32);
  }

  f32x4 o[8] = {};
  float mrow_s = -1e30f, lrow_s = 0.f;   // stats for q-row l15

  stage(0, 0);
  int cur = 0;

  for (int t = 0; t < nt; t++) {
    asm volatile("s_waitcnt vmcnt(0)" ::: "memory");
    __syncthreads();                       // tile t staged & buf cur^1 free
    if (t + 1 < nt) stage(t + 1, cur ^ 1); // prefetch overlaps compute below
    const int kv0 = t * 64;
    if (kv0 <= wmin + 15) {
      // ---- QK^T (swapped: A=K, B=Q) -> sc[f][r] = S[kv0+f*16+lg*4+r][wmin+l15]
      f32x4 sc[4] = {};
#pragma unroll
      for (int f = 0; f < 4; f++) {
        const char* kr = &sK[cur][(f * 16 + l15) * 256];
#pragma unroll
        for (int kk = 0; kk < 4; kk++) {
          short8 kf = *reinterpret_cast<const short8*>(kr + ((kk * 64 + lg * 16) ^ sw));
          sc[f] = __builtin_amdgcn_mfma_f32_16x16x32_bf16(kf, qf[kk], sc[f], 0, 0, 0);
        }
      }
      // ---- causal mask (diagonal tiles only) ----
      if (kv0 + 63 > wmin) {
        const int qa = wmin + l15;
#pragma unroll
        for (int f = 0; f < 4; f++) {
          int kv = kv0 + f * 16 + lg * 4;
#pragma unroll
          for (int r = 0; r < 4; r++)
            if (kv + r > qa) sc[f][r] = -1e30f;
        }
      }
      // ---- online softmax: in-lane over 16 kv, then xor-16/32 across lg ----
      float mx = sc[0][0];
#pragma unroll
      for (int f = 0; f < 4; f++)
#pragma unroll
        for (int r = 0; r < 4; r++) mx = fmaxf(mx, sc[f][r]);
      mx = fmaxf(mx, __shfl_xor(mx, 16));
      mx = fmaxf(mx, __shfl_xor(mx, 32));
      // defer-rescale: only rescale when max grew by > 8
      if (__any(mx > mrow_s + 8.f)) {
        float mn = fmaxf(mrow_s, mx);
        float scl = __expf(mrow_s - mn);
        mrow_s = mn;
        lrow_s *= scl;
        float s4[4];
#pragma unroll
        for (int r = 0; r < 4; r++)
          s4[r] = __shfl(scl, (lane & 48) | (lg * 4 + r));
#pragma unroll
        for (int nf = 0; nf < 8; nf++)
#pragma unroll
          for (int r = 0; r < 4; r++) o[nf][r] *= s4[r];
      }
#pragma unroll
      for (int f = 0; f < 4; f++)
#pragma unroll
        for (int r = 0; r < 4; r++) sc[f][r] = __expf(sc[f][r] - mrow_s);
      float rs = 0.f;
#pragma unroll
      for (int f = 0; f < 4; f++)
        rs += (sc[f][0] + sc[f][1]) + (sc[f][2] + sc[f][3]);
      rs += __shfl_xor(rs, 16);
      rs += __shfl_xor(rs, 32);
      lrow_s += rs;

      // ---- P pack -> 4x ds_write_b64 (row q=l15, bytes = kv*2), swizzled ----
      char* plw = &sP[wid][0];
#pragma unroll
      for (int f = 0; f < 4; f++) {
        uint32_t w0 = (uint32_t)f2bf(sc[f][0]) | ((uint32_t)f2bf(sc[f][1]) << 16);
        uint32_t w1 = (uint32_t)f2bf(sc[f][2]) | ((uint32_t)f2bf(sc[f][3]) << 16);
        *reinterpret_cast<uint2*>(plw + l15 * 128 + ((f * 32 + lg * 8) ^ sw)) =
            make_uint2(w0, w1);
      }
      short8 pa[2];
#pragma unroll
      for (int kk = 0; kk < 2; kk++)
        pa[kk] = *reinterpret_cast<const short8*>(
            plw + l15 * 128 + ((kk * 64 + lg * 16) ^ sw));
      // ---- PV ----
#pragma unroll
      for (int nf = 0; nf < 8; nf++) {
        const char* vr = &sV[cur][(nf * 16 + l15) * 128];
#pragma unroll
        for (int kk = 0; kk < 2; kk++) {
          short8 vb = *reinterpret_cast<const short8*>(vr + ((kk * 64 + lg * 16) ^ sw));
          o[nf] = __builtin_amdgcn_mfma_f32_16x16x32_bf16(pa[kk], vb, o[nf], 0, 0, 0);
        }
      }
    }
    cur ^= 1;
  }

  // fetch l for q-rows lg*4+r (stats live in lanes with l15 == q)
  float lr4[4];
#pragma unroll
  for (int r = 0; r < 4; r++)
    lr4[r] = __shfl(lrow_s, (lane & 48) | (lg * 4 + r));
  unsigned short* cp = ctx + (size_t)(wmin + lg * 4) * Dsz + h * HDn + l15;
#pragma unroll
  for (int nf = 0; nf < 8; nf++)
#pragma unroll
    for (int r = 0; r < 4; r++)
      cp[(size_t)r * Dsz + nf * 16] = f2bf(o[nf][r] / lr4[r]);
}

extern "C" void kernel_launch(void* const* d_in, const int* in_sizes, int n_in,
                              void* d_out, int out_size, void* d_ws, size_t ws_size,
                              hipStream_t stream) {
  (void)in_sizes; (void)n_in; (void)out_size; (void)ws_size;
  const float* x  = (const float*)d_in[0];
  // d_in[1] = mask: causality is hardcoded, never read
  const float* wq = (const float*)d_in[2];
  const float* wk = (const float*)d_in[3];
  const float* wv = (const float*)d_in[4];
  const float* wo = (const float*)d_in[5];
  const float* cs = (const float*)d_in[6];
  const float* sn = (const float*)d_in[7];
  float* out = (float*)d_out;

  unsigned short* ws16  = (unsigned short*)d_ws;
  unsigned short* WTqkv = ws16;                          // 3072*2048 (wq^T|wk^T|wv^T)
  unsigned short* WTo   = WTqkv + 3072 * 2048;           // 2048*2048
  unsigned short* xb    = WTo   + 2048 * 2048;           // 4096*2048
  unsigned short* Qb    = xb    + 4096 * 2048;           // 4096*2048 (rope'd, *1/sqrt(HD))
  unsigned short* Kb    = Qb    + 4096 * 2048;           // 4096*512  (rope'd)
  unsigned short* Vt    = Kb    + 4096 * 512;            // 512*4096  (V transposed)
  unsigned short* ctx   = Vt    + 512 * 4096;            // 4096*2048
  float* Cqkv = (float*)(ctx + 4096 * 2048);             // 4096*3072 f32

  k_cast_bf16<<<4096, 256, 0, stream>>>(x, xb, 4096 * 2048);
  k_transpose<<<dim3(32, 32), 256, 0, stream>>>(wq, 2048, WTqkv,              2048, 2048, 2048);
  k_transpose<<<dim3(8, 32),  256, 0, stream>>>(wk, 512,  WTqkv + 2048 * 2048, 2048, 2048, 512);
  k_transpose<<<dim3(8, 32),  256, 0, stream>>>(wv, 512,  WTqkv + 2560 * 2048, 2048, 2048, 512);
  k_transpose<<<dim3(32, 32), 256, 0, stream>>>(wo, 2048, WTo,                2048, 2048, 2048);

  // Cqkv = xb @ [wq|wk|wv]
  k_gemm256<<<dim3(192), 512, 0, stream>>>(xb, WTqkv, Cqkv, 4096, 3072, 2048, 3072);
  k_rope<<<4096, 256, 0, stream>>>(Cqkv, cs, sn, Qb, Kb);
  // Vt = (Cqkv V-block)^T, cast bf16
  k_transpose<<<dim3(8, 64), 256, 0, stream>>>(Cqkv + 2560, 3072, Vt, 4096, 4096, 512);

  k_attn<<<dim3(512), 512, 0, stream>>>(Qb, Kb, Vt, ctx);

  // out = ctx @ wo
  k_gemm256<<<dim3(128), 512, 0, stream>>>(ctx, WTo, out, 4096, 2048, 2048, 2048);
}

// Round 11
// 418.998 us; speedup vs baseline: 1.0105x; 1.0105x over previous
//
#include <hip/hip_runtime.h>
#include <cstdint>

#define Ssz 4096
#define Dsz 2048
#define Hn  16
#define Gn  4
#define HDn 128

typedef __attribute__((ext_vector_type(8))) short short8;
typedef __attribute__((ext_vector_type(8))) unsigned short u16x8;
typedef __attribute__((ext_vector_type(4))) float f32x4;

typedef __attribute__((address_space(1))) void gbl_void;
typedef __attribute__((address_space(3))) void lds_void;

static __device__ __forceinline__ unsigned short f2bf(float f) {
  uint32_t u = __builtin_bit_cast(uint32_t, f);
  u += 0x7FFFu + ((u >> 16) & 1u);   // RNE (no NaNs in this workload)
  return (unsigned short)(u >> 16);
}

static __device__ __forceinline__ float exp2a(float x) {   // 2^x, native
  float r; asm("v_exp_f32 %0, %1" : "=v"(r) : "v"(x)); return r;
}
static __device__ __forceinline__ uint32_t pkbf(float lo, float hi) {
  uint32_t r; asm("v_cvt_pk_bf16_f32 %0, %1, %2" : "=v"(r) : "v"(lo), "v"(hi));
  return r;
}

// global -> LDS direct copy, 16B per lane. LDS dest is wave-uniform base
// (HW adds lane*16); global source address is per-lane.
static __device__ __forceinline__ void gload_lds16(const void* g, void* l) {
  __builtin_amdgcn_global_load_lds((gbl_void*)(uintptr_t)g,
                                   (lds_void*)(uintptr_t)l, 16, 0, 0);
}

// ---------------- cast f32 -> bf16, 8 elems/thread ----------------
__global__ void k_cast_bf16(const float* __restrict__ src,
                            unsigned short* __restrict__ dst, int n) {
  int base = (blockIdx.x * blockDim.x + threadIdx.x) * 8;
  if (base >= n) return;
  float4 a = *reinterpret_cast<const float4*>(src + base);
  float4 b = *reinterpret_cast<const float4*>(src + base + 4);
  u16x8 o;
  o[0] = f2bf(a.x); o[1] = f2bf(a.y); o[2] = f2bf(a.z); o[3] = f2bf(a.w);
  o[4] = f2bf(b.x); o[5] = f2bf(b.y); o[6] = f2bf(b.z); o[7] = f2bf(b.w);
  *reinterpret_cast<u16x8*>(dst + base) = o;
}

// ---------------- transpose f32 (R x C) -> bf16 (C x R), 64x64 tiles ----------------
__global__ void k_transpose(const float* __restrict__ src, int srcStride,
                            unsigned short* __restrict__ dst, int dstStride,
                            int R, int C) {
  __shared__ unsigned short tile[64][65];
  const int r0 = blockIdx.y * 64, c0 = blockIdx.x * 64;
  const int t  = threadIdx.x;
  const int rr = t >> 2;           // 0..63
  const int cc = (t & 3) * 16;     // 0,16,32,48
  const float* sp = src + (size_t)(r0 + rr) * srcStride + c0 + cc;
#pragma unroll
  for (int j = 0; j < 16; j += 4) {
    float4 v = *reinterpret_cast<const float4*>(sp + j);
    tile[rr][cc + j + 0] = f2bf(v.x);
    tile[rr][cc + j + 1] = f2bf(v.y);
    tile[rr][cc + j + 2] = f2bf(v.z);
    tile[rr][cc + j + 3] = f2bf(v.w);
  }
  __syncthreads();
  unsigned short* dp = dst + (size_t)(c0 + rr) * dstStride + r0 + cc;
  u16x8 o0, o1;
#pragma unroll
  for (int j = 0; j < 8; j++) o0[j] = tile[cc + j][rr];
#pragma unroll
  for (int j = 0; j < 8; j++) o1[j] = tile[cc + 8 + j][rr];
  *reinterpret_cast<u16x8*>(dp)     = o0;
  *reinterpret_cast<u16x8*>(dp + 8) = o1;
}

// ---------------- RoPE on Q (cols 0..2047) and K (cols 2048..2559) of Cqkv ----------------
// Q additionally scaled by log2(e)/sqrt(HD) so attn softmax can use raw exp2.
__global__ void k_rope(const float* __restrict__ Cqkv,
                       const float* __restrict__ cosp, const float* __restrict__ sinp,
                       unsigned short* __restrict__ Qb, unsigned short* __restrict__ Kb) {
  const int s = blockIdx.x;
  const float* row = Cqkv + (size_t)s * 3072;
  const float qscale = 0.12751791525247477f;  // log2(e)/sqrt(128)
  for (int c = threadIdx.x; c < 2560; c += 256) {
    int d = c & 127;
    float v = row[c];
    int pc = (d < 64) ? c + 64 : c - 64;
    float pv = row[pc];
    float rot = (d < 64) ? -pv : pv;
    float o = v * cosp[s * 128 + d] + rot * sinp[s * 128 + d];
    if (c < 2048)
      Qb[(size_t)s * 2048 + c] = f2bf(o * qscale);
    else
      Kb[(size_t)s * 512 + (c - 2048)] = f2bf(o);
  }
}

// ---------------- bf16 GEMM: C(f32, M x N, ldc) = A(M x K) * BT(N x K)^T ----------------
// m97 structure: 128x128 tile, BK=32, 4 waves (2x2), 4x4 16x16x32 frags per wave.
// XCD-aware blockIdx swizzle (grid must be a multiple of 8 blocks).
__global__ __launch_bounds__(256) void k_gemm_bt(
    const unsigned short* __restrict__ A, const unsigned short* __restrict__ BT,
    float* __restrict__ C, int M, int N, int K, int ldc) {
  __shared__ __align__(16) unsigned short sA[128 * 32];
  __shared__ __align__(16) unsigned short sB[128 * 32];
  const int tid = threadIdx.x;
  const int lane = tid & 63, wid = tid >> 6;
  const int bid = blockIdx.y * gridDim.x + blockIdx.x;
  const int cpx = (gridDim.x * gridDim.y) >> 3;
  const int swz = (bid & 7) * cpx + (bid >> 3);
  const int m0 = (swz / gridDim.x) * 128, n0 = (swz % gridDim.x) * 128;
  const int wm = (wid >> 1) * 64, wn = (wid & 1) * 64;
  const int l15 = lane & 15, lg = lane >> 4;
  const int srow = lane >> 2;         // row within 16-row staging chunk
  const int scol = (lane & 3) * 8;    // elem col within BK

  f32x4 acc[4][4] = {};

  for (int kt = 0; kt < K; kt += 32) {
#pragma unroll
    for (int c = 0; c < 2; c++) {
      const int row = c * 64 + wid * 16;
      gload_lds16(A  + (size_t)(m0 + row + srow) * K + kt + scol, sA + row * 32);
      gload_lds16(BT + (size_t)(n0 + row + srow) * K + kt + scol, sB + row * 32);
    }
    __syncthreads();
    short8 af[4], bf[4];
#pragma unroll
    for (int i = 0; i < 4; i++) {
      af[i] = *reinterpret_cast<const short8*>(sA + (wm + i * 16 + l15) * 32 + lg * 8);
      bf[i] = *reinterpret_cast<const short8*>(sB + (wn + i * 16 + l15) * 32 + lg * 8);
    }
#pragma unroll
    for (int i = 0; i < 4; i++)
#pragma unroll
      for (int j = 0; j < 4; j++)
        acc[i][j] = __builtin_amdgcn_mfma_f32_16x16x32_bf16(af[i], bf[j], acc[i][j], 0, 0, 0);
    __syncthreads();
  }

  const int rbase = m0 + wm + lg * 4;
  const int cbase = n0 + wn + l15;
#pragma unroll
  for (int i = 0; i < 4; i++)
#pragma unroll
    for (int j = 0; j < 4; j++)
#pragma unroll
      for (int r = 0; r < 4; r++)
        C[(size_t)(rbase + i * 16 + r) * ldc + cbase + j * 16] = acc[i][j][r];
}

// ---------------- causal GQA flash attention, v5 ----------------
// 4 waves x QBLK=32 (two 16-row m-frags per wave), 128 q/block, 512 blocks.
// Halves per-wave K/V LDS re-reads and per-tile overhead per FLOP vs v4's
// 8x16 shape. Swapped QK^T (lane holds S[kv][q=l15]); per-lane stats per
// m-frag; exp2-domain scores (log2e folded into Q); max3-fusable trees;
// cvt_pk P pack. K/V double-buffered LDS, XOR-swizzled; complement block
// pairing (ids i, i+256 -> tiles 31-j, j) for per-CU load balance.
__global__ __launch_bounds__(256, 2) void k_attn(
    const unsigned short* __restrict__ Qb, const unsigned short* __restrict__ Kb,
    const unsigned short* __restrict__ Vt, unsigned short* __restrict__ ctx) {
  __shared__ __align__(16) char sK[2][16384];   // [buf][64 kv][256B], swizzled
  __shared__ __align__(16) char sV[2][16384];   // [buf][128 d][128B], swizzled
  __shared__ __align__(16) char sP[4][4096];    // [wave][32 q][128B], swizzled
  const int id = blockIdx.x;                    // 0..511
  const int kid = id & 255;
  const int h = kid & 15, g = h >> 2;
  const int j = kid >> 4;                       // 0..15
  const int qt = (id < 256) ? (31 - j) : j;     // long blocks first
  const int qb = qt * 128;
  const int lane = threadIdx.x & 63, wid = threadIdx.x >> 6;  // 4 waves
  const int l15 = lane & 15, lg = lane >> 4;
  const int sw = (l15 & 7) << 4;
  const int wmin = qb + wid * 32;
  const int nt = qt * 2 + 2;

  // per-lane pre-swizzled staging source offsets (bytes)
  const char* kbyte = (const char*)Kb;
  const char* vbyte = (const char*)Vt;
  int kOff[4], vOff[4];
#pragma unroll
  for (int q = 0; q < 4; q++) {
    int rk = wid * 16 + q * 4 + (lane >> 4);            // K tile row 0..63
    kOff[q] = rk * 1024 + g * 256 + (((lane & 15) * 16) ^ ((rk & 7) << 4));
    int rv = wid * 32 + q * 8 + (lane >> 3);            // V tile row (d) 0..127
    vOff[q] = (g * 128 + rv) * 8192 + (((lane & 7) * 16) ^ ((rv & 7) << 4));
  }

  auto stage = [&](int t, int b) {
    const char* ks = kbyte + (size_t)t * 65536;   // kv0*1024
    const char* vs = vbyte + (size_t)t * 128;     // kv0*2
#pragma unroll
    for (int q = 0; q < 4; q++)
      gload_lds16(ks + kOff[q], &sK[b][(wid * 4 + q) * 1024]);
#pragma unroll
    for (int q = 0; q < 4; q++)
      gload_lds16(vs + vOff[q], &sV[b][(wid * 4 + q) * 1024]);
  };

  // hoist Q fragments (L2-resident); B-operand layout: col=q=l15, k=lg*8+i
  short8 qf[2][4];
#pragma unroll
  for (int m = 0; m < 2; m++) {
    const unsigned short* qp = Qb + (size_t)(wmin + m * 16 + l15) * Dsz + h * HDn + lg * 8;
#pragma unroll
    for (int kk = 0; kk < 4; kk++)
      qf[m][kk] = *reinterpret_cast<const short8*>(qp + kk * 32);
  }

  f32x4 o[2][8] = {};
  float ms[2] = {-1e30f, -1e30f}, ls[2] = {0.f, 0.f};  // stats for q-row l15, frag m

  stage(0, 0);
  int cur = 0;

  for (int t = 0; t < nt; t++) {
    asm volatile("s_waitcnt vmcnt(0)" ::: "memory");
    __syncthreads();                       // tile t staged & buf cur^1 free
    if (t + 1 < nt) stage(t + 1, cur ^ 1); // prefetch overlaps compute below
    const int kv0 = t * 64;
    if (kv0 <= wmin + 31) {
      // ---- QK^T (swapped) -> sc[m][f][r] = S'[kv0+f*16+lg*4+r][wmin+m*16+l15]
      f32x4 sc[2][4] = {};
#pragma unroll
      for (int f = 0; f < 4; f++) {
        const char* kr = &sK[cur][(f * 16 + l15) * 256];
#pragma unroll
        for (int kk = 0; kk < 4; kk++) {
          short8 kf = *reinterpret_cast<const short8*>(kr + ((kk * 64 + lg * 16) ^ sw));
          sc[0][f] = __builtin_amdgcn_mfma_f32_16x16x32_bf16(kf, qf[0][kk], sc[0][f], 0, 0, 0);
          sc[1][f] = __builtin_amdgcn_mfma_f32_16x16x32_bf16(kf, qf[1][kk], sc[1][f], 0, 0, 0);
        }
      }
      // ---- causal mask (diagonal tiles only) ----
      if (kv0 + 63 > wmin) {
#pragma unroll
        for (int m = 0; m < 2; m++) {
          const int qa = wmin + m * 16 + l15;
#pragma unroll
          for (int f = 0; f < 4; f++) {
            int kv = kv0 + f * 16 + lg * 4;
#pragma unroll
            for (int r = 0; r < 4; r++)
              if (kv + r > qa) sc[m][f][r] = -1e30f;
          }
        }
      }
      // ---- online softmax (exp2 domain), per m-frag ----
      float mx[2];
#pragma unroll
      for (int m = 0; m < 2; m++) {
        float a0 = fmaxf(fmaxf(sc[m][0][0], sc[m][0][1]), fmaxf(sc[m][0][2], sc[m][0][3]));
        float a1 = fmaxf(fmaxf(sc[m][1][0], sc[m][1][1]), fmaxf(sc[m][1][2], sc[m][1][3]));
        float a2 = fmaxf(fmaxf(sc[m][2][0], sc[m][2][1]), fmaxf(sc[m][2][2], sc[m][2][3]));
        float a3 = fmaxf(fmaxf(sc[m][3][0], sc[m][3][1]), fmaxf(sc[m][3][2], sc[m][3][3]));
        float mv = fmaxf(fmaxf(a0, a1), fmaxf(a2, a3));
        mv = fmaxf(mv, __shfl_xor(mv, 16));
        mv = fmaxf(mv, __shfl_xor(mv, 32));
        mx[m] = mv;
      }
      // defer-rescale: only when max grew by > 8/ln2 in exp2 domain
      if (__any((mx[0] > ms[0] + 11.5f) || (mx[1] > ms[1] + 11.5f))) {
#pragma unroll
        for (int m = 0; m < 2; m++) {
          float mn = fmaxf(ms[m], mx[m]);
          float scl = exp2a(ms[m] - mn);
          ms[m] = mn;
          ls[m] *= scl;
          float s4[4];
#pragma unroll
          for (int r = 0; r < 4; r++)
            s4[r] = __shfl(scl, (lane & 48) | (lg * 4 + r));
#pragma unroll
          for (int nf = 0; nf < 8; nf++)
#pragma unroll
            for (int r = 0; r < 4; r++) o[m][nf][r] *= s4[r];
        }
      }
#pragma unroll
      for (int m = 0; m < 2; m++) {
#pragma unroll
        for (int f = 0; f < 4; f++)
#pragma unroll
          for (int r = 0; r < 4; r++) sc[m][f][r] = exp2a(sc[m][f][r] - ms[m]);
        float rs = ((sc[m][0][0] + sc[m][0][1]) + (sc[m][0][2] + sc[m][0][3]))
                 + ((sc[m][1][0] + sc[m][1][1]) + (sc[m][1][2] + sc[m][1][3]))
                 + ((sc[m][2][0] + sc[m][2][1]) + (sc[m][2][2] + sc[m][2][3]))
                 + ((sc[m][3][0] + sc[m][3][1]) + (sc[m][3][2] + sc[m][3][3]));
        rs += __shfl_xor(rs, 16);
        rs += __shfl_xor(rs, 32);
        ls[m] += rs;
      }
      // ---- P pack (cvt_pk) -> ds_write_b64, swizzled; rows q, bytes=kv*2 ----
      char* plw = &sP[wid][0];
#pragma unroll
      for (int m = 0; m < 2; m++) {
        const int row = m * 16 + l15;
#pragma unroll
        for (int f = 0; f < 4; f++) {
          uint32_t w0 = pkbf(sc[m][f][0], sc[m][f][1]);
          uint32_t w1 = pkbf(sc[m][f][2], sc[m][f][3]);
          *reinterpret_cast<uint2*>(plw + row * 128 + ((f * 32 + lg * 8) ^ sw)) =
              make_uint2(w0, w1);
        }
      }
      short8 pa[2][2];
#pragma unroll
      for (int m = 0; m < 2; m++)
#pragma unroll
        for (int kk = 0; kk < 2; kk++)
          pa[m][kk] = *reinterpret_cast<const short8*>(
              plw + (m * 16 + l15) * 128 + ((kk * 64 + lg * 16) ^ sw));
      // ---- PV (V-frag reused across both m) ----
#pragma unroll
      for (int nf = 0; nf < 8; nf++) {
        const char* vr = &sV[cur][(nf * 16 + l15) * 128];
#pragma unroll
        for (int kk = 0; kk < 2; kk++) {
          short8 vb = *reinterpret_cast<const short8*>(vr + ((kk * 64 + lg * 16) ^ sw));
          o[0][nf] = __builtin_amdgcn_mfma_f32_16x16x32_bf16(pa[0][kk], vb, o[0][nf], 0, 0, 0);
          o[1][nf] = __builtin_amdgcn_mfma_f32_16x16x32_bf16(pa[1][kk], vb, o[1][nf], 0, 0, 0);
        }
      }
    }
    cur ^= 1;
  }

  // stats live in lanes with l15 == within-frag q-row; broadcast per output row
#pragma unroll
  for (int m = 0; m < 2; m++) {
    float lr4[4];
#pragma unroll
    for (int r = 0; r < 4; r++)
      lr4[r] = __shfl(ls[m], (lane & 48) | (lg * 4 + r));
    unsigned short* cp = ctx + (size_t)(wmin + m * 16 + lg * 4) * Dsz + h * HDn + l15;
#pragma unroll
    for (int nf = 0; nf < 8; nf++)
#pragma unroll
      for (int r = 0; r < 4; r++)
        cp[(size_t)r * Dsz + nf * 16] = f2bf(o[m][nf][r] / lr4[r]);
  }
}

extern "C" void kernel_launch(void* const* d_in, const int* in_sizes, int n_in,
                              void* d_out, int out_size, void* d_ws, size_t ws_size,
                              hipStream_t stream) {
  (void)in_sizes; (void)n_in; (void)out_size; (void)ws_size;
  const float* x  = (const float*)d_in[0];
  // d_in[1] = mask: causality is hardcoded, never read
  const float* wq = (const float*)d_in[2];
  const float* wk = (const float*)d_in[3];
  const float* wv = (const float*)d_in[4];
  const float* wo = (const float*)d_in[5];
  const float* cs = (const float*)d_in[6];
  const float* sn = (const float*)d_in[7];
  float* out = (float*)d_out;

  unsigned short* ws16  = (unsigned short*)d_ws;
  unsigned short* WTqkv = ws16;                          // 3072*2048 (wq^T|wk^T|wv^T)
  unsigned short* WTo   = WTqkv + 3072 * 2048;           // 2048*2048
  unsigned short* xb    = WTo   + 2048 * 2048;           // 4096*2048
  unsigned short* Qb    = xb    + 4096 * 2048;           // 4096*2048 (rope'd, *log2e/sqrt(HD))
  unsigned short* Kb    = Qb    + 4096 * 2048;           // 4096*512  (rope'd)
  unsigned short* Vt    = Kb    + 4096 * 512;            // 512*4096  (V transposed)
  unsigned short* ctx   = Vt    + 512 * 4096;            // 4096*2048
  float* Cqkv = (float*)(ctx + 4096 * 2048);             // 4096*3072 f32

  k_cast_bf16<<<4096, 256, 0, stream>>>(x, xb, 4096 * 2048);
  k_transpose<<<dim3(32, 32), 256, 0, stream>>>(wq, 2048, WTqkv,              2048, 2048, 2048);
  k_transpose<<<dim3(8, 32),  256, 0, stream>>>(wk, 512,  WTqkv + 2048 * 2048, 2048, 2048, 512);
  k_transpose<<<dim3(8, 32),  256, 0, stream>>>(wv, 512,  WTqkv + 2560 * 2048, 2048, 2048, 512);
  k_transpose<<<dim3(32, 32), 256, 0, stream>>>(wo, 2048, WTo,                2048, 2048, 2048);

  // Cqkv = xb @ [wq|wk|wv]
  k_gemm_bt<<<dim3(24, 32), 256, 0, stream>>>(xb, WTqkv, Cqkv, 4096, 3072, 2048, 3072);
  k_rope<<<4096, 256, 0, stream>>>(Cqkv, cs, sn, Qb, Kb);
  // Vt = (Cqkv V-block)^T, cast bf16
  k_transpose<<<dim3(8, 64), 256, 0, stream>>>(Cqkv + 2560, 3072, Vt, 4096, 4096, 512);

  k_attn<<<dim3(512), 256, 0, stream>>>(Qb, Kb, Vt, ctx);

  // out = ctx @ wo
  k_gemm_bt<<<dim3(16, 32), 256, 0, stream>>>(ctx, WTo, out, 4096, 2048, 2048, 2048);
}